// Round 13
// baseline (521.525 us; speedup 1.0000x reference)
//
#include <hip/hip_runtime.h>

// ---------------------------------------------------------------------------
// Transformer block w/ SimilarityMaps branch. fp32 inputs/outputs; weights
// canonicalized to bf16; GEMMs + attention on MFMA (16x16x32 bf16).
// B=8 N=1024 C=768 H=12 hd=64 K_PARTS=64 HID=3072. Tokens M = 8192.
// Round 21: BN=64 tile variant (128x64, 768 blocks = 3/CU balanced) for the
//   two lone 384-block GEMMs (cproj step 11, fc2 step 14). At 1.5 blocks/CU
//   half the CUs ran one latency-starved block (R2: 74 us at 16% HBM; fc2 =
//   fc1's FLOPs but 4x fewer blocks). Sync structure unchanged; only the
//   N-extent / vmcnt count / fragment j-range specialize.
// ---------------------------------------------------------------------------

typedef unsigned short u16;
typedef unsigned int   u32;
typedef __attribute__((ext_vector_type(8))) short short8;       // bf16 x8 frag
typedef __attribute__((ext_vector_type(8))) unsigned short ushort8v;
typedef __attribute__((ext_vector_type(4))) float f32x4;        // MFMA accum

#define F_GELU     1
#define F_RES1     4    // bf16 residual (res1)
#define F_RESF     8    // fp32 residual (resf)
#define F_OUTB     16   // write bf16 to out
#define F_OUTF     32   // write fp32 to outf
#define F_BIAS     64   // fp32 bias

__device__ __forceinline__ float bf2f(u32 b) { return __uint_as_float(b << 16); }
__device__ __forceinline__ u16 f2bf(float f) {
    u32 u = __float_as_uint(f);
    u32 r = u + 0x7fffu + ((u >> 16) & 1u);   // RNE
    return (u16)(r >> 16);
}
__device__ __forceinline__ u16 f2bf_fast(float f) {
    return (u16)((__float_as_uint(f) + 0x8000u) >> 16);
}
__device__ __forceinline__ float gelu_exact(float v) {
    return 0.5f * v * (1.0f + erff(v * 0.70710678118654752440f));
}
// tanh-form GELU (max abs dev from exact ~3e-3; cheap: 1 transcendental)
__device__ __forceinline__ float gelu_fast(float x) {
    float u = 0.79788456080286535588f * (x + 0.044715f * x * x * x);
    float e = __builtin_amdgcn_exp2f(u * 2.88539008177792681472f);  // exp(2u)
    float t = 1.0f - 2.0f / (e + 1.0f);
    return 0.5f * x * (1.0f + t);
}

// async global->LDS, 16 B per lane; lds base must be wave-uniform
__device__ __forceinline__ void gload16(const u16* g, u16* l) {
    __builtin_amdgcn_global_load_lds(
        (const __attribute__((address_space(1))) u32*)g,
        (__attribute__((address_space(3))) u32*)l, 16, 0, 0);
}

// ---------------- prologue bodies (conv / pn / ln) -------------------------
struct ConvArgs {
    const float* src[8];
    u16*         dst[8];
    int          nblk[9];   // cumulative block offsets
    int          n[8];
};

__device__ __forceinline__ void conv_body(const ConvArgs& a, int b)
{
    int i = 0;
    #pragma unroll
    for (int j = 0; j < 7; j++) if (b >= a.nblk[j + 1]) i = j + 1;
    const int base = (b - a.nblk[i]) * 1024 + threadIdx.x * 4;
    if (base >= a.n[i]) return;
    float4 v = *(const float4*)(a.src[i] + base);
    ushort4 o;
    o.x = f2bf(v.x); o.y = f2bf(v.y); o.z = f2bf(v.z); o.w = f2bf(v.w);
    *(ushort4*)(a.dst[i] + base) = o;
}

__device__ __forceinline__ float block_sum(float v, float* red) {
    #pragma unroll
    for (int off = 32; off > 0; off >>= 1) v += __shfl_down(v, off);
    __syncthreads();
    if ((threadIdx.x & 63) == 0) red[threadIdx.x >> 6] = v;
    __syncthreads();
    return red[0] + red[1] + red[2] + red[3];
}

__device__ __forceinline__ void pn_body(const float* __restrict__ P,
                                        u16* __restrict__ Pn, int row, float* red)
{
    const int t = threadIdx.x;
    float v[3];
    #pragma unroll
    for (int i = 0; i < 3; i++)
        v[i] = P[(size_t)row * 768 + t + i * 256];
    float tot = block_sum(v[0]*v[0] + v[1]*v[1] + v[2]*v[2], red);
    float inv = rsqrtf(tot);
    #pragma unroll
    for (int i = 0; i < 3; i++)
        Pn[(size_t)row * 768 + t + i * 256] = f2bf(v[i] * inv);
}

template<bool NORM>
__device__ __forceinline__ void ln_body(const float* __restrict__ xin,
                                        const float* __restrict__ g,
                                        const float* __restrict__ bta,
                                        u16* __restrict__ out,
                                        float* __restrict__ invnorm,
                                        int row, float* red)
{
    const int t = threadIdx.x;
    float v[3];
    #pragma unroll
    for (int i = 0; i < 3; i++)
        v[i] = xin[(size_t)row * 768 + t + i * 256];
    float tot = block_sum(v[0] + v[1] + v[2], red);
    float mu  = tot * (1.0f / 768.0f);
    float d0 = v[0] - mu, d1 = v[1] - mu, d2 = v[2] - mu;
    float tot2 = block_sum(d0 * d0 + d1 * d1 + d2 * d2, red);
    float rstd = rsqrtf(tot2 * (1.0f / 768.0f) + 1e-5f);
    float ss = 0.0f;
    #pragma unroll
    for (int i = 0; i < 3; i++) {
        int c = t + i * 256;
        float yy = (v[i] - mu) * rstd * g[c] + bta[c];
        out[(size_t)row * 768 + c] = f2bf(yy);
        ss += yy * yy;
    }
    if constexpr (NORM) {
        float tot3 = block_sum(ss, red);
        if (t == 0) invnorm[row] = rsqrtf(tot3);
    }
}

// fused prologue: conv (weights) + pn (P rows) + ln1 (x) in one launch
struct PrepArgs {
    ConvArgs conv;
    const float* P;   u16* Pn;
    const float* x;   const float* g; const float* bta;
    u16* n1;          float* invn;
    int conv_blocks;
};

__global__ __launch_bounds__(256)
void prep_k(PrepArgs pa)
{
    __shared__ float red[4];
    const int b = blockIdx.x;
    if (b < pa.conv_blocks) {
        conv_body(pa.conv, b);
    } else if (b < pa.conv_blocks + 64) {
        pn_body(pa.P, pa.Pn, b - pa.conv_blocks, red);
    } else {
        ln_body<true>(pa.x, pa.g, pa.bta, pa.n1, pa.invn,
                      b - pa.conv_blocks - 64, red);
    }
}

// standalone LN (step 12)
template<bool NORM>
__global__ __launch_bounds__(256)
void ln_k(const float* __restrict__ xin, const float* __restrict__ g,
          const float* __restrict__ bta, u16* __restrict__ out,
          float* __restrict__ invnorm)
{
    __shared__ float red[4];
    ln_body<NORM>(xin, g, bta, out, invnorm, blockIdx.x, red);
}

// ---------------- MFMA GEMM body: C[M,N] = A[M,K] * W[N,K]^T ---------------
// 128xBN tile (BN=128 or 64), BK=32. BN=128: 4 waves as 2Mx2N of 64x64.
// BN=64: 4 waves as 2Mx2N of 64x32. Triple-buffered LDS, 2-deep prefetch,
// one barrier per K-iter. XCD-chunked block order, col-grouping G=6
// (requires gridDim.x % 6 == 0). Per-buf u16 size PB = 4096 + BN*32.
template<int FLAGS, int BN = 128>
__device__ __forceinline__
void gemm_body(int orig, int nbx, int nby,
               const u16* __restrict__ A, const u16* __restrict__ W,
               const float* __restrict__ bias,
               const u16* __restrict__ res1, const float* __restrict__ resf,
               u16* __restrict__ out, float* __restrict__ outf,
               int M, int N, int K, u16* smem_)
{
    constexpr int PB = 4096 + BN * 32;         // u16 per buffer
    constexpr int JN = BN / 32;                // col frags per wave (4 or 2)
    constexpr int CW = BN / 2;                 // cols per wave (64 or 32)
    constexpr int SEGW = CW / 4;               // cols per lane segment (16 or 8)
    const int t = threadIdx.x;
    const int wave = t >> 6, lane = t & 63;
    const int cpx  = (nbx * nby) >> 3;         // wgs per XCD chunk
    const int xcd  = orig & 7, loc = orig >> 3;
    const int Rc   = cpx / nbx;                // rows per chunk
    const int gsz  = 6 * Rc;                   // wgs per col-group
    const int grp  = loc / gsz;
    const int rem  = loc - grp * gsz;
    const int ccol = grp * 6 + rem % 6;
    const int crow = xcd * Rc + rem / 6;
    const int m0 = crow * 128, n0 = ccol * BN;
    const int Wm = (wave >> 1) * 64, Wn = (wave & 1) * CW;
    const int rr = lane >> 2, cc = (lane & 3) * 8;
    const int quad = lane >> 4, r16 = lane & 15;
    const int NK = K >> 5;

    f32x4 acc[4][JN];
    #pragma unroll
    for (int i = 0; i < 4; i++)
        #pragma unroll
        for (int j = 0; j < JN; j++)
            acc[i][j] = (f32x4){0.f, 0.f, 0.f, 0.f};

    // staging: A = 8 chunks of 16 rows (all BN); B = BN/16 chunks.
    // BN=128: B chunks = wave*2+c (2/wave); BN=64: B chunk = wave (1/wave).
    auto stage = [&](int k0, int buf) {
        u16* base = smem_ + buf * PB;
        #pragma unroll
        for (int c = 0; c < 2; c++) {
            const int chunk = wave * 2 + c;
            const int row = chunk * 16 + rr;
            gload16(A + (size_t)(m0 + row) * K + k0 + cc, base + chunk * 512);
        }
        if constexpr (BN == 128) {
            #pragma unroll
            for (int c = 0; c < 2; c++) {
                const int chunk = wave * 2 + c;
                const int row = chunk * 16 + rr;
                gload16(W + (size_t)(n0 + row) * K + k0 + cc,
                        base + 4096 + chunk * 512);
            }
        } else {
            const int row = wave * 16 + rr;
            gload16(W + (size_t)(n0 + row) * K + k0 + cc,
                    base + 4096 + wave * 512);
        }
    };

    // prologue: stage k-tiles 0 and 1 into bufs 0,1
    stage(0, 0);
    if (NK > 1) stage(32, 1);

    for (int kt = 0; kt < NK; kt++) {
        const int cur = kt % 3;
        if (kt + 1 < NK) {
            if constexpr (BN == 128)
                asm volatile("s_waitcnt vmcnt(4)\n\ts_barrier" ::: "memory");
            else
                asm volatile("s_waitcnt vmcnt(3)\n\ts_barrier" ::: "memory");
        } else {
            asm volatile("s_waitcnt vmcnt(0)\n\ts_barrier" ::: "memory");
        }
        if (kt + 2 < NK)
            stage((kt + 2) * 32, (kt + 2) % 3);
        short8 af[4], bfr[JN];
        #pragma unroll
        for (int i = 0; i < 4; i++)
            af[i] = *(const short8*)&smem_[cur * PB + (Wm + i * 16 + r16) * 32 + quad * 8];
        #pragma unroll
        for (int j = 0; j < JN; j++)
            bfr[j] = *(const short8*)&smem_[cur * PB + 4096 + (Wn + j * 16 + r16) * 32 + quad * 8];
        #pragma unroll
        for (int i = 0; i < 4; i++)
            #pragma unroll
            for (int j = 0; j < JN; j++)
                acc[i][j] = __builtin_amdgcn_mfma_f32_16x16x32_bf16(
                    af[i], bfr[j], acc[i][j], 0, 0, 0);
    }
    __syncthreads();

    // ---- epilogue: wave-private fp32 repack (no cross-wave sync) ----
    float* myl = (float*)smem_ + wave * 1088;   // 16 rows x 68 cols fp32
    float bj[JN];
    #pragma unroll
    for (int j = 0; j < JN; j++) {
        if constexpr (FLAGS & F_BIAS) bj[j] = bias[n0 + Wn + j * 16 + r16];
        else bj[j] = 0.0f;
    }
    const int row = lane >> 2, seg = (lane & 3) * SEGW;

    #pragma unroll
    for (int i = 0; i < 4; i++) {
        #pragma unroll
        for (int j = 0; j < JN; j++)
            #pragma unroll
            for (int r = 0; r < 4; r++) {
                float v = acc[i][j][r] + bj[j];
                if constexpr (FLAGS & F_GELU) v = gelu_fast(v);
                myl[(quad * 4 + r) * 68 + j * 16 + r16] = v;
            }
        float v[SEGW];
        #pragma unroll
        for (int k4 = 0; k4 < SEGW / 4; k4++) {
            float4 f = *(const float4*)&myl[row * 68 + seg + k4 * 4];
            v[k4 * 4 + 0] = f.x; v[k4 * 4 + 1] = f.y;
            v[k4 * 4 + 2] = f.z; v[k4 * 4 + 3] = f.w;
        }
        const int m = m0 + Wm + i * 16 + row;
        const size_t idx = (size_t)m * N + n0 + Wn + seg;
        if constexpr (FLAGS & F_RES1) {
            #pragma unroll
            for (int k8 = 0; k8 < SEGW / 8; k8++) {
                ushort8v r0 = *(const ushort8v*)(res1 + idx + k8 * 8);
                #pragma unroll
                for (int k = 0; k < 8; k++) v[k8 * 8 + k] += bf2f(r0[k]);
            }
        }
        if constexpr (FLAGS & F_RESF) {
            #pragma unroll
            for (int k4 = 0; k4 < SEGW / 4; k4++) {
                float4 f = *(const float4*)(resf + idx + k4 * 4);
                v[k4 * 4 + 0] += f.x; v[k4 * 4 + 1] += f.y;
                v[k4 * 4 + 2] += f.z; v[k4 * 4 + 3] += f.w;
            }
        }
        if constexpr (FLAGS & F_OUTB) {
            #pragma unroll
            for (int k8 = 0; k8 < SEGW / 8; k8++) {
                ushort8v o0;
                #pragma unroll
                for (int k = 0; k < 8; k++) o0[k] = f2bf(v[k8 * 8 + k]);
                *(ushort8v*)(out + idx + k8 * 8) = o0;
            }
        }
        if constexpr (FLAGS & F_OUTF) {
            #pragma unroll
            for (int k4 = 0; k4 < SEGW / 4; k4++) {
                float4 f = {v[k4 * 4 + 0], v[k4 * 4 + 1], v[k4 * 4 + 2], v[k4 * 4 + 3]};
                *(float4*)(outf + idx + k4 * 4) = f;
            }
        }
    }
}

template<int FLAGS, int BN = 128>
__global__ __launch_bounds__(256)
void gemm_mfma(const u16* __restrict__ A, const u16* __restrict__ W,
               const float* __restrict__ bias,
               const u16* __restrict__ res1, const float* __restrict__ resf,
               u16* __restrict__ out, float* __restrict__ outf,
               int M, int N, int K)
{
    __shared__ u16 smem[3 * (4096 + BN * 32)];
    gemm_body<FLAGS, BN>(blockIdx.x + blockIdx.y * gridDim.x,
                         gridDim.x, gridDim.y,
                         A, W, bias, res1, resf, out, outf, M, N, K, smem);
}

// proj (K=768) and zin (K=64) co-resident: blocks [0,384) proj, [384,768) zin.
__global__ __launch_bounds__(256)
void gemm_pair_k(const u16* __restrict__ A0, const u16* __restrict__ W0,
                 const float* __restrict__ b0, u16* __restrict__ o0, int K0,
                 const u16* __restrict__ A1, const u16* __restrict__ W1,
                 const float* __restrict__ b1, u16* __restrict__ o1, int K1)
{
    __shared__ u16 smem[3 * 8192];
    if (blockIdx.x < 384)
        gemm_body<F_BIAS | F_OUTB>(blockIdx.x, 6, 64, A0, W0, b0,
                                   nullptr, nullptr, o0, nullptr,
                                   8192, 768, K0, smem);
    else
        gemm_body<F_BIAS | F_OUTB>(blockIdx.x - 384, 6, 64, A1, W1, b1,
                                   nullptr, nullptr, o1, nullptr,
                                   8192, 768, K1, smem);
}

// ---------------- dmap body: dmap=(n1@Pn^T)*invn ; cph=gelu(dmap@W1^T+b) ---
// 64-row blocks (128 total). Shared arrays carved from the caller's 48 KB:
//   Asm f32[16][68] | Wsm f32[16][68] | Dsm u16[64][66] | W1s u16[64][66]
__device__ void dmap_body(const u16* __restrict__ A, const u16* __restrict__ Pn,
                          const float* __restrict__ invn,
                          const u16* __restrict__ w1, const float* __restrict__ b1,
                          float* __restrict__ dmap_f, u16* __restrict__ cph,
                          int blk, u16* smembase)
{
    float* Asm = (float*)smembase;          // [16][68]
    float* Wsm = Asm + 16 * 68;             // [16][68]
    u16*   Dsm = (u16*)(Wsm + 16 * 68);     // [64][66]
    u16*   W1s = Dsm + 64 * 66;             // [64][66]
    const int t  = threadIdx.x;
    const int tx = t & 15, ty = t >> 4;
    const int m0 = blk * 64;

    {
        const int r = t >> 2, c = (t & 3) * 16;
        #pragma unroll
        for (int k = 0; k < 16; k++)
            W1s[r * 66 + c + k] = w1[r * 64 + c + k];
    }

    float acc[4][4];
    #pragma unroll
    for (int i = 0; i < 4; i++)
        #pragma unroll
        for (int j = 0; j < 4; j++) acc[i][j] = 0.0f;

    for (int k0 = 0; k0 < 768; k0 += 16) {
        {
            int r = t >> 2, c4 = (t & 3) << 2;
            uint2 u = *(const uint2*)(A + (size_t)(m0 + r) * 768 + k0 + c4);
            Asm[(c4 + 0) * 68 + r] = bf2f(u.x & 0xffffu);
            Asm[(c4 + 1) * 68 + r] = bf2f(u.x >> 16);
            Asm[(c4 + 2) * 68 + r] = bf2f(u.y & 0xffffu);
            Asm[(c4 + 3) * 68 + r] = bf2f(u.y >> 16);
        }
        {
            int r = t >> 2, c4 = (t & 3) << 2;
            uint2 u = *(const uint2*)(Pn + (size_t)r * 768 + k0 + c4);
            Wsm[(c4 + 0) * 68 + r] = bf2f(u.x & 0xffffu);
            Wsm[(c4 + 1) * 68 + r] = bf2f(u.x >> 16);
            Wsm[(c4 + 2) * 68 + r] = bf2f(u.y & 0xffffu);
            Wsm[(c4 + 3) * 68 + r] = bf2f(u.y >> 16);
        }
        __syncthreads();
        #pragma unroll
        for (int k = 0; k < 16; k++) {
            float a[4], w[4];
            float4 va = *(const float4*)&Asm[k * 68 + ty * 4];
            a[0] = va.x; a[1] = va.y; a[2] = va.z; a[3] = va.w;
            float4 vw = *(const float4*)&Wsm[k * 68 + tx * 4];
            w[0] = vw.x; w[1] = vw.y; w[2] = vw.z; w[3] = vw.w;
            #pragma unroll
            for (int i = 0; i < 4; i++)
                #pragma unroll
                for (int j = 0; j < 4; j++)
                    acc[i][j] = fmaf(a[i], w[j], acc[i][j]);
        }
        __syncthreads();
    }

    #pragma unroll
    for (int i = 0; i < 4; i++) {
        const int m = m0 + ty * 4 + i;
        const float rs = invn[m];
        float4 o4;
        float e0 = acc[i][0] * rs, e1 = acc[i][1] * rs;
        float e2 = acc[i][2] * rs, e3 = acc[i][3] * rs;
        o4.x = e0; o4.y = e1; o4.z = e2; o4.w = e3;
        *(float4*)(dmap_f + (size_t)m * 64 + tx * 4) = o4;
        const int rl = ty * 4 + i;
        Dsm[rl * 66 + tx * 4 + 0] = f2bf(e0);
        Dsm[rl * 66 + tx * 4 + 1] = f2bf(e1);
        Dsm[rl * 66 + tx * 4 + 2] = f2bf(e2);
        Dsm[rl * 66 + tx * 4 + 3] = f2bf(e3);
    }
    __syncthreads();

    float acc2[4][4];
    #pragma unroll
    for (int i = 0; i < 4; i++)
        #pragma unroll
        for (int j = 0; j < 4; j++) acc2[i][j] = 0.0f;
    for (int k4 = 0; k4 < 16; k4++) {
        float d[4][4], w[4][4];
        #pragma unroll
        for (int i = 0; i < 4; i++) {
            u32 u0 = *(const u32*)&Dsm[(ty * 4 + i) * 66 + k4 * 4];
            u32 u1 = *(const u32*)&Dsm[(ty * 4 + i) * 66 + k4 * 4 + 2];
            d[i][0] = bf2f(u0 & 0xffffu); d[i][1] = bf2f(u0 >> 16);
            d[i][2] = bf2f(u1 & 0xffffu); d[i][3] = bf2f(u1 >> 16);
        }
        #pragma unroll
        for (int j = 0; j < 4; j++) {
            u32 u0 = *(const u32*)&W1s[(tx * 4 + j) * 66 + k4 * 4];
            u32 u1 = *(const u32*)&W1s[(tx * 4 + j) * 66 + k4 * 4 + 2];
            w[j][0] = bf2f(u0 & 0xffffu); w[j][1] = bf2f(u0 >> 16);
            w[j][2] = bf2f(u1 & 0xffffu); w[j][3] = bf2f(u1 >> 16);
        }
        #pragma unroll
        for (int i = 0; i < 4; i++)
            #pragma unroll
            for (int j = 0; j < 4; j++)
                #pragma unroll
                for (int kk = 0; kk < 4; kk++)
                    acc2[i][j] = fmaf(d[i][kk], w[j][kk], acc2[i][j]);
    }
    {
        float4 bv = *(const float4*)(b1 + tx * 4);
        float b4[4] = {bv.x, bv.y, bv.z, bv.w};
        #pragma unroll
        for (int i = 0; i < 4; i++) {
            const int m = m0 + ty * 4 + i;
            ushort4 o4;
            o4.x = f2bf(gelu_exact(acc2[i][0] + b4[0]));
            o4.y = f2bf(gelu_exact(acc2[i][1] + b4[1]));
            o4.z = f2bf(gelu_exact(acc2[i][2] + b4[2]));
            o4.w = f2bf(gelu_exact(acc2[i][3] + b4[3]));
            *(ushort4*)(cph + (size_t)m * 64 + tx * 4) = o4;
        }
    }
}

// merged launch: blocks [0,128) = dmap branch (starts at t=0, hidden under
// qkv); blocks [128,1280) = qkv GEMM on a virtual (18,64) grid.
__global__ __launch_bounds__(256)
void qkv_dmap_k(const u16* __restrict__ A, const u16* __restrict__ Wq,
                const float* __restrict__ bq, u16* __restrict__ outq,
                const u16* __restrict__ Pn, const float* __restrict__ invn,
                const u16* __restrict__ w1, const float* __restrict__ b1,
                float* __restrict__ dmap_f, u16* __restrict__ cph)
{
    __shared__ u16 smem[3 * 8192];
    if (blockIdx.x < 128)
        dmap_body(A, Pn, invn, w1, b1, dmap_f, cph, blockIdx.x, smem);
    else
        gemm_body<F_BIAS | F_OUTB>(blockIdx.x - 128, 18, 64, A, Wq, bq,
                                   nullptr, nullptr, outq, nullptr,
                                   8192, 2304, 768, smem);
}

// ---------------- MFMA flash attention (bf16, max-free online softmax) ----
__global__ __launch_bounds__(256)
void attn_mfma(const u16* __restrict__ qkv, u16* __restrict__ out)
{
    const int orig = blockIdx.x + blockIdx.y * 8;
    const int wg   = (orig & 7) * 96 + (orig >> 3);
    const int qt = wg & 7;                // 0..7  (128-row q tiles)
    const int bh = wg >> 3;               // 0..95
    const int b = bh / 12, h = bh % 12;
    __shared__ u16 Qs[2 * 128 * 32];      // 16 KB
    __shared__ u16 Ks[2 * 64 * 32];       //  8 KB
    __shared__ u16 Vt[2 * 64 * 32];       //  8 KB  (transposed: rows = d)
    __shared__ u16 Ps[2 * 128 * 32];      // 16 KB; epilogue: 4 waves x 2 x 16x64
    const int t = threadIdx.x;
    const int wave = t >> 6, lane = t & 63;
    const int quad = lane >> 4, r16 = lane & 15;
    const size_t RS = 2304;
    const int tok0 = b * 1024 + qt * 128;
    const u16* qbase = qkv + (size_t)tok0 * RS + h * 64;
    const float SC = 0.125f * 1.44269504088896340736f;   // scale * log2(e)

    #pragma unroll
    for (int c = 0; c < 4; c++) {
        int idx = wave * 4 + c;
        int kc = idx >> 3, rg = idx & 7;
        int row = rg * 16 + (lane >> 2);
        gload16(qbase + (size_t)row * RS + kc * 32 + (lane & 3) * 8,
                &Qs[kc * 4096 + rg * 512]);
    }

    f32x4 O[2][4];
    float lpart[2][4];
    #pragma unroll
    for (int i = 0; i < 2; i++)
        #pragma unroll
        for (int j = 0; j < 4; j++) {
            O[i][j] = (f32x4){0.f, 0.f, 0.f, 0.f};
            lpart[i][j & 3] = 0.0f;
        }

    // staging helpers
    const int kp = t & 63, dg = t >> 6;
    const int vb = (kp >> 5) * 2048 + (kp & 31);
    uint2 vr[4];

    // prologue: stage kt=0 (K-DMA into Ks, V into regs)
    {
        const u16* kbase = qkv + (size_t)(b * 1024) * RS + 768 + h * 64;
        #pragma unroll
        for (int c = 0; c < 2; c++) {
            int idx = wave * 2 + c;
            int kc = idx >> 2, rg = idx & 3;
            int row = rg * 16 + (lane >> 2);
            gload16(kbase + (size_t)row * RS + kc * 32 + (lane & 3) * 8,
                    &Ks[kc * 2048 + rg * 512]);
        }
        const u16* vbase = qkv + (size_t)(b * 1024) * RS + 1536 + h * 64;
        #pragma unroll
        for (int it = 0; it < 4; it++) {
            int d0 = dg * 16 + it * 4;
            vr[it] = *(const uint2*)(vbase + (size_t)kp * RS + d0);
        }
    }

    for (int kt = 0; kt < 16; kt++) {
        __syncthreads();
        #pragma unroll
        for (int it = 0; it < 4; it++) {
            int d0 = dg * 16 + it * 4;
            uint2 u = vr[it];
            Vt[vb + (d0 + 0) * 32] = (u16)(u.x & 0xffffu);
            Vt[vb + (d0 + 1) * 32] = (u16)(u.x >> 16);
            Vt[vb + (d0 + 2) * 32] = (u16)(u.y & 0xffffu);
            Vt[vb + (d0 + 3) * 32] = (u16)(u.y >> 16);
        }

        f32x4 S[2][4];
        #pragma unroll
        for (int i = 0; i < 2; i++)
            #pragma unroll
            for (int j = 0; j < 4; j++)
                S[i][j] = (f32x4){0.f, 0.f, 0.f, 0.f};
        __builtin_amdgcn_s_setprio(1);
        #pragma unroll
        for (int kc = 0; kc < 2; kc++) {
            short8 aq[2], bk[4];
            #pragma unroll
            for (int i = 0; i < 2; i++)
                aq[i] = *(const short8*)&Qs[kc * 4096 + (wave * 32 + i * 16 + r16) * 32 + quad * 8];
            #pragma unroll
            for (int j = 0; j < 4; j++)
                bk[j] = *(const short8*)&Ks[kc * 2048 + (j * 16 + r16) * 32 + quad * 8];
            #pragma unroll
            for (int i = 0; i < 2; i++)
                #pragma unroll
                for (int j = 0; j < 4; j++)
                    S[i][j] = __builtin_amdgcn_mfma_f32_16x16x32_bf16(
                        aq[i], bk[j], S[i][j], 0, 0, 0);
        }
        __builtin_amdgcn_s_setprio(0);

        #pragma unroll
        for (int i = 0; i < 2; i++) {
            #pragma unroll
            for (int j = 0; j < 4; j++) {
                const int col = j * 16 + r16;
                const int pb = (col >> 5) * 4096 + (col & 31);
                #pragma unroll
                for (int r = 0; r < 4; r++) {
                    float p = __builtin_amdgcn_exp2f(S[i][j][r] * SC);
                    lpart[i][r] += p;
                    const int row = wave * 32 + i * 16 + quad * 4 + r;
                    Ps[pb + row * 32] = f2bf_fast(p);
                }
            }
        }

        __syncthreads();

        if (kt < 15) {
            const u16* kbase = qkv + (size_t)(b * 1024 + (kt + 1) * 64) * RS + 768 + h * 64;
            #pragma unroll
            for (int c = 0; c < 2; c++) {
                int idx = wave * 2 + c;
                int kc = idx >> 2, rg = idx & 3;
                int row = rg * 16 + (lane >> 2);
                gload16(kbase + (size_t)row * RS + kc * 32 + (lane & 3) * 8,
                        &Ks[kc * 2048 + rg * 512]);
            }
            const u16* vbase = qkv + (size_t)(b * 1024 + (kt + 1) * 64) * RS + 1536 + h * 64;
            #pragma unroll
            for (int it = 0; it < 4; it++) {
                int d0 = dg * 16 + it * 4;
                vr[it] = *(const uint2*)(vbase + (size_t)kp * RS + d0);
            }
        }

        __builtin_amdgcn_s_setprio(1);
        #pragma unroll
        for (int kc = 0; kc < 2; kc++) {
            short8 ap[2], bv[4];
            #pragma unroll
            for (int i = 0; i < 2; i++)
                ap[i] = *(const short8*)&Ps[kc * 4096 + (wave * 32 + i * 16 + r16) * 32 + quad * 8];
            #pragma unroll
            for (int j = 0; j < 4; j++)
                bv[j] = *(const short8*)&Vt[kc * 2048 + (j * 16 + r16) * 32 + quad * 8];
            #pragma unroll
            for (int i = 0; i < 2; i++)
                #pragma unroll
                for (int j = 0; j < 4; j++)
                    O[i][j] = __builtin_amdgcn_mfma_f32_16x16x32_bf16(
                        ap[i], bv[j], O[i][j], 0, 0, 0);
        }
        __builtin_amdgcn_s_setprio(0);
    }

    // epilogue: wave-private repack through Ps (dead), coalesced 16B stores
    const int row = lane >> 2, seg = (lane & 3) * 16;
    #pragma unroll
    for (int i = 0; i < 2; i++) {
        float linv[4];
        #pragma unroll
        for (int r = 0; r < 4; r++) {
            float l = lpart[i][r];
            l += __shfl_xor(l, 1);
            l += __shfl_xor(l, 2);
            l += __shfl_xor(l, 4);
            l += __shfl_xor(l, 8);
            linv[r] = 1.0f / l;
        }
        u16* myl = &Ps[wave * 2048 + i * 1024];   // 16 rows x 64 cols
        #pragma unroll
        for (int j = 0; j < 4; j++)
            #pragma unroll
            for (int r = 0; r < 4; r++)
                myl[(quad * 4 + r) * 64 + j * 16 + r16] = f2bf(O[i][j][r] * linv[r]);
        const int token = tok0 + wave * 32 + i * 16 + row;
        const size_t oidx = (size_t)token * 768 + h * 64 + seg;
        *(ushort8v*)(out + oidx)     = *(const ushort8v*)&myl[row * 64 + seg];
        *(ushort8v*)(out + oidx + 8) = *(const ushort8v*)&myl[row * 64 + seg + 8];
    }
}

// ---------------------------------------------------------------------------
extern "C" void kernel_launch(void* const* d_in, const int* in_sizes, int n_in,
                              void* d_out, int out_size, void* d_ws, size_t ws_size,
                              hipStream_t stream)
{
    (void)in_sizes; (void)n_in; (void)out_size; (void)ws_size;
    const float* x        = (const float*)d_in[0];
    const float* ln1_g    = (const float*)d_in[1];
    const float* ln1_b    = (const float*)d_in[2];
    const float* qkv_w    = (const float*)d_in[3];
    const float* qkv_b    = (const float*)d_in[4];
    const float* proj_w   = (const float*)d_in[5];
    const float* proj_b   = (const float*)d_in[6];
    const float* c_qkv_w  = (const float*)d_in[7];
    const float* c_qkv_b  = (const float*)d_in[8];
    const float* c_proj_w = (const float*)d_in[9];
    const float* c_proj_b = (const float*)d_in[10];
    const float* cp_fc1_w = (const float*)d_in[11];
    const float* cp_fc1_b = (const float*)d_in[12];
    const float* cp_fc2_w = (const float*)d_in[13];
    const float* cp_fc2_b = (const float*)d_in[14];
    const float* P        = (const float*)d_in[15];
    const float* ln2_g    = (const float*)d_in[16];
    const float* ln2_b    = (const float*)d_in[17];
    const float* fc1_w    = (const float*)d_in[18];
    const float* fc1_b    = (const float*)d_in[19];
    const float* fc2_w    = (const float*)d_in[20];
    const float* fc2_b    = (const float*)d_in[21];

    float* out_x    = (float*)d_out;               // (8,1024,768) fp32
    float* out_dmap = out_x + 6291456;             // (8,1024,64)  fp32

    // ws layout (u16 element units)
    u16* us    = (u16*)d_ws;
    u16* n1n2  = us;                         //  6291456  n1 -> zin -> n2
    u16* bigA  = us + 6291456;               // 25165824  qkv/qkv2 ; h(3072)
    u16* ao    = bigA + 18874368;            //  6291456  attn out (tail)
    u16* y     = us + 31457280;              //  6291456
    float* xs  = (float*)(us + 37748736);    //  6291456 fp32
    u16* cph   = us + 50855936;              //   524288
    u16* Pn    = us + 51380224;              //    49152
    float* invn = (float*)(us + 51429376);   //  8192 fp32
    u16* ci    = us + 51445760;              //  canonical bf16 weights

    u16* w_qkv   = ci;                  // 1769472
    u16* w_proj  = ci + 1769472;        // 589824
    u16* w_cqkv  = ci + 2359296;        // 1769472
    u16* w_cproj = ci + 4128768;        // 589824
    u16* w_cpf1  = ci + 4718592;        // 4096
    u16* w_cpf2  = ci + 4722688;        // 49152
    u16* w_fc1   = ci + 4771840;        // 2359296
    u16* w_fc2   = ci + 7131136;        // 2359296

    // 0-2. fused prologue: weight conv + P-normalize + LN1
    {
        PrepArgs pa;
        const float* wsrc[8] = { qkv_w, proj_w, c_qkv_w, c_proj_w,
                                 cp_fc1_w, cp_fc2_w, fc1_w, fc2_w };
        u16* wdst[8] = { w_qkv, w_proj, w_cqkv, w_cproj,
                         w_cpf1, w_cpf2, w_fc1, w_fc2 };
        const int wn[8] = { 1769472, 589824, 1769472, 589824,
                            4096, 49152, 2359296, 2359296 };
        int cum = 0;
        for (int i = 0; i < 8; i++) {
            pa.conv.src[i] = wsrc[i]; pa.conv.dst[i] = wdst[i];
            pa.conv.n[i] = wn[i];
            pa.conv.nblk[i] = cum;
            cum += (wn[i] / 4 + 255) / 256;
        }
        pa.conv.nblk[8] = cum;
        pa.conv_blocks = cum;
        pa.P = P; pa.Pn = Pn;
        pa.x = x; pa.g = ln1_g; pa.bta = ln1_b;
        pa.n1 = n1n2; pa.invn = invn;
        prep_k<<<cum + 64 + 8192, 256, 0, stream>>>(pa);
    }

    // 3 + dmap branch, co-resident: qkv GEMM || (dmap fp32 + cph)
    qkv_dmap_k<<<1280, 256, 0, stream>>>(n1n2, w_qkv, qkv_b, bigA,
                                         Pn, invn, w_cpf1, cp_fc1_b,
                                         out_dmap, cph);
    // 4. attention 1
    attn_mfma<<<dim3(8, 96), 256, 0, stream>>>(bigA, ao);
    // 5+8. co-resident: y = ao @ proj_w^T + b  ||  zin = cph @ cp_fc2_w^T + b
    gemm_pair_k<<<768, 256, 0, stream>>>(ao, w_proj, proj_b, y, 768,
                                         cph, w_cpf2, cp_fc2_b, n1n2, 64);
    // 9. qkv2 = zin @ c_qkv_w^T + b
    gemm_mfma<F_BIAS | F_OUTB>
        <<<dim3(18, 64), 256, 0, stream>>>(n1n2, w_cqkv, c_qkv_b, nullptr, nullptr,
                                           bigA, nullptr, 8192, 2304, 768);
    // 10. attention 2
    attn_mfma<<<dim3(8, 96), 256, 0, stream>>>(bigA, ao);
    // 11. xs = ao2 @ c_proj_w^T + b + y + x  (BN=64: 768 blocks, 3/CU)
    gemm_mfma<F_BIAS | F_RES1 | F_RESF | F_OUTF, 64>
        <<<dim3(12, 64), 256, 0, stream>>>(ao, w_cproj, c_proj_b, y, x,
                                           nullptr, xs, 8192, 768, 768);
    // 12. n2 = LN(xs)
    ln_k<false><<<8192, 256, 0, stream>>>(xs, ln2_g, ln2_b, n1n2, nullptr);
    // 13. h = gelu(n2 @ fc1_w^T + b)
    gemm_mfma<F_BIAS | F_GELU | F_OUTB>
        <<<dim3(24, 64), 256, 0, stream>>>(n1n2, w_fc1, fc1_b, nullptr, nullptr,
                                           bigA, nullptr, 8192, 3072, 768);
    // 14. out = h @ fc2_w^T + b + xs  (BN=64: 768 blocks, 3/CU)
    gemm_mfma<F_BIAS | F_RESF | F_OUTF, 64>
        <<<dim3(12, 64), 256, 0, stream>>>(bigA, w_fc2, fc2_b, nullptr, xs,
                                           nullptr, out_x, 8192, 768, 3072);
}

// Round 14
// 511.303 us; speedup vs baseline: 1.0200x; 1.0200x over previous
//
#include <hip/hip_runtime.h>

// ---------------------------------------------------------------------------
// Transformer block w/ SimilarityMaps branch. fp32 inputs/outputs; weights
// canonicalized to bf16; GEMMs + attention on MFMA (16x16x32 bf16).
// B=8 N=1024 C=768 H=12 hd=64 K_PARTS=64 HID=3072. Tokens M = 8192.
// Round 22: REVERT BN=64 (R13 regressed: halved tile width doubles A-fetch,
//   79.6 MB observed vs 33; same invariant as R11's dmap split). Restore the
//   best-measured session config (R10/R12, 508.3 us): BN=128 everywhere,
//   prep fusion, dmap-under-qkv merge, proj||zin pair, XCD-chunked
//   col-grouped order, 3-buf 2-deep prefetch, 1 barrier/K-iter.
// ---------------------------------------------------------------------------

typedef unsigned short u16;
typedef unsigned int   u32;
typedef __attribute__((ext_vector_type(8))) short short8;       // bf16 x8 frag
typedef __attribute__((ext_vector_type(8))) unsigned short ushort8v;
typedef __attribute__((ext_vector_type(4))) float f32x4;        // MFMA accum

#define F_GELU     1
#define F_RES1     4    // bf16 residual (res1)
#define F_RESF     8    // fp32 residual (resf)
#define F_OUTB     16   // write bf16 to out
#define F_OUTF     32   // write fp32 to outf
#define F_BIAS     64   // fp32 bias

__device__ __forceinline__ float bf2f(u32 b) { return __uint_as_float(b << 16); }
__device__ __forceinline__ u16 f2bf(float f) {
    u32 u = __float_as_uint(f);
    u32 r = u + 0x7fffu + ((u >> 16) & 1u);   // RNE
    return (u16)(r >> 16);
}
__device__ __forceinline__ u16 f2bf_fast(float f) {
    return (u16)((__float_as_uint(f) + 0x8000u) >> 16);
}
__device__ __forceinline__ float gelu_exact(float v) {
    return 0.5f * v * (1.0f + erff(v * 0.70710678118654752440f));
}
// tanh-form GELU (max abs dev from exact ~3e-3; cheap: 1 transcendental)
__device__ __forceinline__ float gelu_fast(float x) {
    float u = 0.79788456080286535588f * (x + 0.044715f * x * x * x);
    float e = __builtin_amdgcn_exp2f(u * 2.88539008177792681472f);  // exp(2u)
    float t = 1.0f - 2.0f / (e + 1.0f);
    return 0.5f * x * (1.0f + t);
}

// async global->LDS, 16 B per lane; lds base must be wave-uniform
__device__ __forceinline__ void gload16(const u16* g, u16* l) {
    __builtin_amdgcn_global_load_lds(
        (const __attribute__((address_space(1))) u32*)g,
        (__attribute__((address_space(3))) u32*)l, 16, 0, 0);
}

// ---------------- prologue bodies (conv / pn / ln) -------------------------
struct ConvArgs {
    const float* src[8];
    u16*         dst[8];
    int          nblk[9];   // cumulative block offsets
    int          n[8];
};

__device__ __forceinline__ void conv_body(const ConvArgs& a, int b)
{
    int i = 0;
    #pragma unroll
    for (int j = 0; j < 7; j++) if (b >= a.nblk[j + 1]) i = j + 1;
    const int base = (b - a.nblk[i]) * 1024 + threadIdx.x * 4;
    if (base >= a.n[i]) return;
    float4 v = *(const float4*)(a.src[i] + base);
    ushort4 o;
    o.x = f2bf(v.x); o.y = f2bf(v.y); o.z = f2bf(v.z); o.w = f2bf(v.w);
    *(ushort4*)(a.dst[i] + base) = o;
}

__device__ __forceinline__ float block_sum(float v, float* red) {
    #pragma unroll
    for (int off = 32; off > 0; off >>= 1) v += __shfl_down(v, off);
    __syncthreads();
    if ((threadIdx.x & 63) == 0) red[threadIdx.x >> 6] = v;
    __syncthreads();
    return red[0] + red[1] + red[2] + red[3];
}

__device__ __forceinline__ void pn_body(const float* __restrict__ P,
                                        u16* __restrict__ Pn, int row, float* red)
{
    const int t = threadIdx.x;
    float v[3];
    #pragma unroll
    for (int i = 0; i < 3; i++)
        v[i] = P[(size_t)row * 768 + t + i * 256];
    float tot = block_sum(v[0]*v[0] + v[1]*v[1] + v[2]*v[2], red);
    float inv = rsqrtf(tot);
    #pragma unroll
    for (int i = 0; i < 3; i++)
        Pn[(size_t)row * 768 + t + i * 256] = f2bf(v[i] * inv);
}

template<bool NORM>
__device__ __forceinline__ void ln_body(const float* __restrict__ xin,
                                        const float* __restrict__ g,
                                        const float* __restrict__ bta,
                                        u16* __restrict__ out,
                                        float* __restrict__ invnorm,
                                        int row, float* red)
{
    const int t = threadIdx.x;
    float v[3];
    #pragma unroll
    for (int i = 0; i < 3; i++)
        v[i] = xin[(size_t)row * 768 + t + i * 256];
    float tot = block_sum(v[0] + v[1] + v[2], red);
    float mu  = tot * (1.0f / 768.0f);
    float d0 = v[0] - mu, d1 = v[1] - mu, d2 = v[2] - mu;
    float tot2 = block_sum(d0 * d0 + d1 * d1 + d2 * d2, red);
    float rstd = rsqrtf(tot2 * (1.0f / 768.0f) + 1e-5f);
    float ss = 0.0f;
    #pragma unroll
    for (int i = 0; i < 3; i++) {
        int c = t + i * 256;
        float yy = (v[i] - mu) * rstd * g[c] + bta[c];
        out[(size_t)row * 768 + c] = f2bf(yy);
        ss += yy * yy;
    }
    if constexpr (NORM) {
        float tot3 = block_sum(ss, red);
        if (t == 0) invnorm[row] = rsqrtf(tot3);
    }
}

// fused prologue: conv (weights) + pn (P rows) + ln1 (x) in one launch
struct PrepArgs {
    ConvArgs conv;
    const float* P;   u16* Pn;
    const float* x;   const float* g; const float* bta;
    u16* n1;          float* invn;
    int conv_blocks;
};

__global__ __launch_bounds__(256)
void prep_k(PrepArgs pa)
{
    __shared__ float red[4];
    const int b = blockIdx.x;
    if (b < pa.conv_blocks) {
        conv_body(pa.conv, b);
    } else if (b < pa.conv_blocks + 64) {
        pn_body(pa.P, pa.Pn, b - pa.conv_blocks, red);
    } else {
        ln_body<true>(pa.x, pa.g, pa.bta, pa.n1, pa.invn,
                      b - pa.conv_blocks - 64, red);
    }
}

// standalone LN (step 12)
template<bool NORM>
__global__ __launch_bounds__(256)
void ln_k(const float* __restrict__ xin, const float* __restrict__ g,
          const float* __restrict__ bta, u16* __restrict__ out,
          float* __restrict__ invnorm)
{
    __shared__ float red[4];
    ln_body<NORM>(xin, g, bta, out, invnorm, blockIdx.x, red);
}

// ---------------- MFMA GEMM body: C[M,N] = A[M,K] * W[N,K]^T ---------------
// 128x128 tile, BK=32; 4 waves, each a 64x64 sub-tile. Triple-buffered LDS,
// 2-deep prefetch, one barrier per K-iter. XCD-chunked block order with
// intra-chunk col-grouping (G=6). smem_ = 3*8192 u16 (48 KB).
template<int FLAGS>
__device__ __forceinline__
void gemm_body(int orig, int nbx, int nby,
               const u16* __restrict__ A, const u16* __restrict__ W,
               const float* __restrict__ bias,
               const u16* __restrict__ res1, const float* __restrict__ resf,
               u16* __restrict__ out, float* __restrict__ outf,
               int M, int N, int K, u16* smem_)
{
    const int t = threadIdx.x;
    const int wave = t >> 6, lane = t & 63;
    const int cpx  = (nbx * nby) >> 3;         // wgs per XCD chunk
    const int xcd  = orig & 7, loc = orig >> 3;
    const int Rc   = cpx / nbx;                // rows per chunk
    const int gsz  = 6 * Rc;                   // wgs per col-group
    const int grp  = loc / gsz;
    const int rem  = loc - grp * gsz;
    const int ccol = grp * 6 + rem % 6;
    const int crow = xcd * Rc + rem / 6;
    const int m0 = crow * 128, n0 = ccol * 128;
    const int Wm = (wave >> 1) * 64, Wn = (wave & 1) * 64;
    const int rr = lane >> 2, cc = (lane & 3) * 8;
    const int quad = lane >> 4, r16 = lane & 15;
    const int NK = K >> 5;

    f32x4 acc[4][4];
    #pragma unroll
    for (int i = 0; i < 4; i++)
        #pragma unroll
        for (int j = 0; j < 4; j++)
            acc[i][j] = (f32x4){0.f, 0.f, 0.f, 0.f};

    // prologue: stage k-tiles 0 and 1 into bufs 0,1 (order matters for vmcnt)
    #pragma unroll
    for (int c = 0; c < 2; c++) {
        const int chunk = wave * 2 + c;
        const int row = chunk * 16 + rr;
        gload16(A + (size_t)(m0 + row) * K + cc, smem_ + chunk * 512);
        gload16(W + (size_t)(n0 + row) * K + cc, smem_ + 4096 + chunk * 512);
    }
    if (NK > 1) {
        #pragma unroll
        for (int c = 0; c < 2; c++) {
            const int chunk = wave * 2 + c;
            const int row = chunk * 16 + rr;
            gload16(A + (size_t)(m0 + row) * K + 32 + cc, smem_ + 8192 + chunk * 512);
            gload16(W + (size_t)(n0 + row) * K + 32 + cc, smem_ + 12288 + chunk * 512);
        }
    }

    for (int kt = 0; kt < NK; kt++) {
        const int cur = kt % 3;
        if (kt + 1 < NK)
            asm volatile("s_waitcnt vmcnt(4)\n\ts_barrier" ::: "memory");
        else
            asm volatile("s_waitcnt vmcnt(0)\n\ts_barrier" ::: "memory");
        if (kt + 2 < NK) {
            const int k0 = (kt + 2) * 32;
            const int nb = (kt + 2) % 3;
            #pragma unroll
            for (int c = 0; c < 2; c++) {
                const int chunk = wave * 2 + c;
                const int row = chunk * 16 + rr;
                gload16(A + (size_t)(m0 + row) * K + k0 + cc,
                        smem_ + nb * 8192 + chunk * 512);
                gload16(W + (size_t)(n0 + row) * K + k0 + cc,
                        smem_ + nb * 8192 + 4096 + chunk * 512);
            }
        }
        short8 af[4], bfr[4];
        #pragma unroll
        for (int i = 0; i < 4; i++) {
            af[i]  = *(const short8*)&smem_[cur * 8192 + (Wm + i * 16 + r16) * 32 + quad * 8];
            bfr[i] = *(const short8*)&smem_[cur * 8192 + 4096 + (Wn + i * 16 + r16) * 32 + quad * 8];
        }
        #pragma unroll
        for (int i = 0; i < 4; i++)
            #pragma unroll
            for (int j = 0; j < 4; j++)
                acc[i][j] = __builtin_amdgcn_mfma_f32_16x16x32_bf16(
                    af[i], bfr[j], acc[i][j], 0, 0, 0);
    }
    __syncthreads();

    // ---- epilogue: wave-private fp32 repack (no cross-wave sync) ----
    float* myl = (float*)smem_ + wave * 1088;   // 16 rows x 68 cols fp32
    float bj[4];
    #pragma unroll
    for (int j = 0; j < 4; j++) {
        if constexpr (FLAGS & F_BIAS) bj[j] = bias[n0 + Wn + j * 16 + r16];
        else bj[j] = 0.0f;
    }
    const int row = lane >> 2, seg = (lane & 3) * 16;

    #pragma unroll
    for (int i = 0; i < 4; i++) {
        #pragma unroll
        for (int j = 0; j < 4; j++)
            #pragma unroll
            for (int r = 0; r < 4; r++) {
                float v = acc[i][j][r] + bj[j];
                if constexpr (FLAGS & F_GELU) v = gelu_fast(v);
                myl[(quad * 4 + r) * 68 + j * 16 + r16] = v;
            }
        float v[16];
        #pragma unroll
        for (int k4 = 0; k4 < 4; k4++) {
            float4 f = *(const float4*)&myl[row * 68 + seg + k4 * 4];
            v[k4 * 4 + 0] = f.x; v[k4 * 4 + 1] = f.y;
            v[k4 * 4 + 2] = f.z; v[k4 * 4 + 3] = f.w;
        }
        const int m = m0 + Wm + i * 16 + row;
        const size_t idx = (size_t)m * N + n0 + Wn + seg;
        if constexpr (FLAGS & F_RES1) {
            ushort8v r0 = *(const ushort8v*)(res1 + idx);
            ushort8v r1 = *(const ushort8v*)(res1 + idx + 8);
            #pragma unroll
            for (int k = 0; k < 8; k++) { v[k] += bf2f(r0[k]); v[k + 8] += bf2f(r1[k]); }
        }
        if constexpr (FLAGS & F_RESF) {
            #pragma unroll
            for (int k4 = 0; k4 < 4; k4++) {
                float4 f = *(const float4*)(resf + idx + k4 * 4);
                v[k4 * 4 + 0] += f.x; v[k4 * 4 + 1] += f.y;
                v[k4 * 4 + 2] += f.z; v[k4 * 4 + 3] += f.w;
            }
        }
        if constexpr (FLAGS & F_OUTB) {
            ushort8v o0, o1;
            #pragma unroll
            for (int k = 0; k < 8; k++) { o0[k] = f2bf(v[k]); o1[k] = f2bf(v[k + 8]); }
            *(ushort8v*)(out + idx) = o0;
            *(ushort8v*)(out + idx + 8) = o1;
        }
        if constexpr (FLAGS & F_OUTF) {
            #pragma unroll
            for (int k4 = 0; k4 < 4; k4++) {
                float4 f = {v[k4 * 4 + 0], v[k4 * 4 + 1], v[k4 * 4 + 2], v[k4 * 4 + 3]};
                *(float4*)(outf + idx + k4 * 4) = f;
            }
        }
    }
}

template<int FLAGS>
__global__ __launch_bounds__(256)
void gemm_mfma(const u16* __restrict__ A, const u16* __restrict__ W,
               const float* __restrict__ bias,
               const u16* __restrict__ res1, const float* __restrict__ resf,
               u16* __restrict__ out, float* __restrict__ outf,
               int M, int N, int K)
{
    __shared__ u16 smem[3][8192];
    gemm_body<FLAGS>(blockIdx.x + blockIdx.y * gridDim.x, gridDim.x, gridDim.y,
                     A, W, bias, res1, resf, out, outf, M, N, K, &smem[0][0]);
}

// proj (K=768) and zin (K=64) co-resident: blocks [0,384) proj, [384,768) zin.
__global__ __launch_bounds__(256)
void gemm_pair_k(const u16* __restrict__ A0, const u16* __restrict__ W0,
                 const float* __restrict__ b0, u16* __restrict__ o0, int K0,
                 const u16* __restrict__ A1, const u16* __restrict__ W1,
                 const float* __restrict__ b1, u16* __restrict__ o1, int K1)
{
    __shared__ u16 smem[3][8192];
    if (blockIdx.x < 384)
        gemm_body<F_BIAS | F_OUTB>(blockIdx.x, 6, 64, A0, W0, b0,
                                   nullptr, nullptr, o0, nullptr,
                                   8192, 768, K0, &smem[0][0]);
    else
        gemm_body<F_BIAS | F_OUTB>(blockIdx.x - 384, 6, 64, A1, W1, b1,
                                   nullptr, nullptr, o1, nullptr,
                                   8192, 768, K1, &smem[0][0]);
}

// ---------------- dmap body: dmap=(n1@Pn^T)*invn ; cph=gelu(dmap@W1^T+b) ---
// 64-row blocks (128 total). Shared arrays carved from the caller's 48 KB:
//   Asm f32[16][68] | Wsm f32[16][68] | Dsm u16[64][66] | W1s u16[64][66]
__device__ void dmap_body(const u16* __restrict__ A, const u16* __restrict__ Pn,
                          const float* __restrict__ invn,
                          const u16* __restrict__ w1, const float* __restrict__ b1,
                          float* __restrict__ dmap_f, u16* __restrict__ cph,
                          int blk, u16* smembase)
{
    float* Asm = (float*)smembase;          // [16][68]
    float* Wsm = Asm + 16 * 68;             // [16][68]
    u16*   Dsm = (u16*)(Wsm + 16 * 68);     // [64][66]
    u16*   W1s = Dsm + 64 * 66;             // [64][66]
    const int t  = threadIdx.x;
    const int tx = t & 15, ty = t >> 4;
    const int m0 = blk * 64;

    {
        const int r = t >> 2, c = (t & 3) * 16;
        #pragma unroll
        for (int k = 0; k < 16; k++)
            W1s[r * 66 + c + k] = w1[r * 64 + c + k];
    }

    float acc[4][4];
    #pragma unroll
    for (int i = 0; i < 4; i++)
        #pragma unroll
        for (int j = 0; j < 4; j++) acc[i][j] = 0.0f;

    for (int k0 = 0; k0 < 768; k0 += 16) {
        {
            int r = t >> 2, c4 = (t & 3) << 2;
            uint2 u = *(const uint2*)(A + (size_t)(m0 + r) * 768 + k0 + c4);
            Asm[(c4 + 0) * 68 + r] = bf2f(u.x & 0xffffu);
            Asm[(c4 + 1) * 68 + r] = bf2f(u.x >> 16);
            Asm[(c4 + 2) * 68 + r] = bf2f(u.y & 0xffffu);
            Asm[(c4 + 3) * 68 + r] = bf2f(u.y >> 16);
        }
        {
            int r = t >> 2, c4 = (t & 3) << 2;
            uint2 u = *(const uint2*)(Pn + (size_t)r * 768 + k0 + c4);
            Wsm[(c4 + 0) * 68 + r] = bf2f(u.x & 0xffffu);
            Wsm[(c4 + 1) * 68 + r] = bf2f(u.x >> 16);
            Wsm[(c4 + 2) * 68 + r] = bf2f(u.y & 0xffffu);
            Wsm[(c4 + 3) * 68 + r] = bf2f(u.y >> 16);
        }
        __syncthreads();
        #pragma unroll
        for (int k = 0; k < 16; k++) {
            float a[4], w[4];
            float4 va = *(const float4*)&Asm[k * 68 + ty * 4];
            a[0] = va.x; a[1] = va.y; a[2] = va.z; a[3] = va.w;
            float4 vw = *(const float4*)&Wsm[k * 68 + tx * 4];
            w[0] = vw.x; w[1] = vw.y; w[2] = vw.z; w[3] = vw.w;
            #pragma unroll
            for (int i = 0; i < 4; i++)
                #pragma unroll
                for (int j = 0; j < 4; j++)
                    acc[i][j] = fmaf(a[i], w[j], acc[i][j]);
        }
        __syncthreads();
    }

    #pragma unroll
    for (int i = 0; i < 4; i++) {
        const int m = m0 + ty * 4 + i;
        const float rs = invn[m];
        float4 o4;
        float e0 = acc[i][0] * rs, e1 = acc[i][1] * rs;
        float e2 = acc[i][2] * rs, e3 = acc[i][3] * rs;
        o4.x = e0; o4.y = e1; o4.z = e2; o4.w = e3;
        *(float4*)(dmap_f + (size_t)m * 64 + tx * 4) = o4;
        const int rl = ty * 4 + i;
        Dsm[rl * 66 + tx * 4 + 0] = f2bf(e0);
        Dsm[rl * 66 + tx * 4 + 1] = f2bf(e1);
        Dsm[rl * 66 + tx * 4 + 2] = f2bf(e2);
        Dsm[rl * 66 + tx * 4 + 3] = f2bf(e3);
    }
    __syncthreads();

    float acc2[4][4];
    #pragma unroll
    for (int i = 0; i < 4; i++)
        #pragma unroll
        for (int j = 0; j < 4; j++) acc2[i][j] = 0.0f;
    for (int k4 = 0; k4 < 16; k4++) {
        float d[4][4], w[4][4];
        #pragma unroll
        for (int i = 0; i < 4; i++) {
            u32 u0 = *(const u32*)&Dsm[(ty * 4 + i) * 66 + k4 * 4];
            u32 u1 = *(const u32*)&Dsm[(ty * 4 + i) * 66 + k4 * 4 + 2];
            d[i][0] = bf2f(u0 & 0xffffu); d[i][1] = bf2f(u0 >> 16);
            d[i][2] = bf2f(u1 & 0xffffu); d[i][3] = bf2f(u1 >> 16);
        }
        #pragma unroll
        for (int j = 0; j < 4; j++) {
            u32 u0 = *(const u32*)&W1s[(tx * 4 + j) * 66 + k4 * 4];
            u32 u1 = *(const u32*)&W1s[(tx * 4 + j) * 66 + k4 * 4 + 2];
            w[j][0] = bf2f(u0 & 0xffffu); w[j][1] = bf2f(u0 >> 16);
            w[j][2] = bf2f(u1 & 0xffffu); w[j][3] = bf2f(u1 >> 16);
        }
        #pragma unroll
        for (int i = 0; i < 4; i++)
            #pragma unroll
            for (int j = 0; j < 4; j++)
                #pragma unroll
                for (int kk = 0; kk < 4; kk++)
                    acc2[i][j] = fmaf(d[i][kk], w[j][kk], acc2[i][j]);
    }
    {
        float4 bv = *(const float4*)(b1 + tx * 4);
        float b4[4] = {bv.x, bv.y, bv.z, bv.w};
        #pragma unroll
        for (int i = 0; i < 4; i++) {
            const int m = m0 + ty * 4 + i;
            ushort4 o4;
            o4.x = f2bf(gelu_exact(acc2[i][0] + b4[0]));
            o4.y = f2bf(gelu_exact(acc2[i][1] + b4[1]));
            o4.z = f2bf(gelu_exact(acc2[i][2] + b4[2]));
            o4.w = f2bf(gelu_exact(acc2[i][3] + b4[3]));
            *(ushort4*)(cph + (size_t)m * 64 + tx * 4) = o4;
        }
    }
}

// merged launch: blocks [0,128) = dmap branch (starts at t=0, hidden under
// qkv); blocks [128,1280) = qkv GEMM on a virtual (18,64) grid.
__global__ __launch_bounds__(256)
void qkv_dmap_k(const u16* __restrict__ A, const u16* __restrict__ Wq,
                const float* __restrict__ bq, u16* __restrict__ outq,
                const u16* __restrict__ Pn, const float* __restrict__ invn,
                const u16* __restrict__ w1, const float* __restrict__ b1,
                float* __restrict__ dmap_f, u16* __restrict__ cph)
{
    __shared__ u16 smem[3][8192];
    if (blockIdx.x < 128)
        dmap_body(A, Pn, invn, w1, b1, dmap_f, cph, blockIdx.x, &smem[0][0]);
    else
        gemm_body<F_BIAS | F_OUTB>(blockIdx.x - 128, 18, 64, A, Wq, bq,
                                   nullptr, nullptr, outq, nullptr,
                                   8192, 2304, 768, &smem[0][0]);
}

// ---------------- MFMA flash attention (bf16, max-free online softmax) ----
__global__ __launch_bounds__(256)
void attn_mfma(const u16* __restrict__ qkv, u16* __restrict__ out)
{
    const int orig = blockIdx.x + blockIdx.y * 8;
    const int wg   = (orig & 7) * 96 + (orig >> 3);
    const int qt = wg & 7;                // 0..7  (128-row q tiles)
    const int bh = wg >> 3;               // 0..95
    const int b = bh / 12, h = bh % 12;
    __shared__ u16 Qs[2 * 128 * 32];      // 16 KB
    __shared__ u16 Ks[2 * 64 * 32];       //  8 KB
    __shared__ u16 Vt[2 * 64 * 32];       //  8 KB  (transposed: rows = d)
    __shared__ u16 Ps[2 * 128 * 32];      // 16 KB; epilogue: 4 waves x 2 x 16x64
    const int t = threadIdx.x;
    const int wave = t >> 6, lane = t & 63;
    const int quad = lane >> 4, r16 = lane & 15;
    const size_t RS = 2304;
    const int tok0 = b * 1024 + qt * 128;
    const u16* qbase = qkv + (size_t)tok0 * RS + h * 64;
    const float SC = 0.125f * 1.44269504088896340736f;   // scale * log2(e)

    #pragma unroll
    for (int c = 0; c < 4; c++) {
        int idx = wave * 4 + c;
        int kc = idx >> 3, rg = idx & 7;
        int row = rg * 16 + (lane >> 2);
        gload16(qbase + (size_t)row * RS + kc * 32 + (lane & 3) * 8,
                &Qs[kc * 4096 + rg * 512]);
    }

    f32x4 O[2][4];
    float lpart[2][4];
    #pragma unroll
    for (int i = 0; i < 2; i++)
        #pragma unroll
        for (int j = 0; j < 4; j++) {
            O[i][j] = (f32x4){0.f, 0.f, 0.f, 0.f};
            lpart[i][j & 3] = 0.0f;
        }

    // staging helpers
    const int kp = t & 63, dg = t >> 6;
    const int vb = (kp >> 5) * 2048 + (kp & 31);
    uint2 vr[4];

    // prologue: stage kt=0 (K-DMA into Ks, V into regs)
    {
        const u16* kbase = qkv + (size_t)(b * 1024) * RS + 768 + h * 64;
        #pragma unroll
        for (int c = 0; c < 2; c++) {
            int idx = wave * 2 + c;
            int kc = idx >> 2, rg = idx & 3;
            int row = rg * 16 + (lane >> 2);
            gload16(kbase + (size_t)row * RS + kc * 32 + (lane & 3) * 8,
                    &Ks[kc * 2048 + rg * 512]);
        }
        const u16* vbase = qkv + (size_t)(b * 1024) * RS + 1536 + h * 64;
        #pragma unroll
        for (int it = 0; it < 4; it++) {
            int d0 = dg * 16 + it * 4;
            vr[it] = *(const uint2*)(vbase + (size_t)kp * RS + d0);
        }
    }

    for (int kt = 0; kt < 16; kt++) {
        __syncthreads();
        #pragma unroll
        for (int it = 0; it < 4; it++) {
            int d0 = dg * 16 + it * 4;
            uint2 u = vr[it];
            Vt[vb + (d0 + 0) * 32] = (u16)(u.x & 0xffffu);
            Vt[vb + (d0 + 1) * 32] = (u16)(u.x >> 16);
            Vt[vb + (d0 + 2) * 32] = (u16)(u.y & 0xffffu);
            Vt[vb + (d0 + 3) * 32] = (u16)(u.y >> 16);
        }

        f32x4 S[2][4];
        #pragma unroll
        for (int i = 0; i < 2; i++)
            #pragma unroll
            for (int j = 0; j < 4; j++)
                S[i][j] = (f32x4){0.f, 0.f, 0.f, 0.f};
        __builtin_amdgcn_s_setprio(1);
        #pragma unroll
        for (int kc = 0; kc < 2; kc++) {
            short8 aq[2], bk[4];
            #pragma unroll
            for (int i = 0; i < 2; i++)
                aq[i] = *(const short8*)&Qs[kc * 4096 + (wave * 32 + i * 16 + r16) * 32 + quad * 8];
            #pragma unroll
            for (int j = 0; j < 4; j++)
                bk[j] = *(const short8*)&Ks[kc * 2048 + (j * 16 + r16) * 32 + quad * 8];
            #pragma unroll
            for (int i = 0; i < 2; i++)
                #pragma unroll
                for (int j = 0; j < 4; j++)
                    S[i][j] = __builtin_amdgcn_mfma_f32_16x16x32_bf16(
                        aq[i], bk[j], S[i][j], 0, 0, 0);
        }
        __builtin_amdgcn_s_setprio(0);

        #pragma unroll
        for (int i = 0; i < 2; i++) {
            #pragma unroll
            for (int j = 0; j < 4; j++) {
                const int col = j * 16 + r16;
                const int pb = (col >> 5) * 4096 + (col & 31);
                #pragma unroll
                for (int r = 0; r < 4; r++) {
                    float p = __builtin_amdgcn_exp2f(S[i][j][r] * SC);
                    lpart[i][r] += p;
                    const int row = wave * 32 + i * 16 + quad * 4 + r;
                    Ps[pb + row * 32] = f2bf_fast(p);
                }
            }
        }

        __syncthreads();

        if (kt < 15) {
            const u16* kbase = qkv + (size_t)(b * 1024 + (kt + 1) * 64) * RS + 768 + h * 64;
            #pragma unroll
            for (int c = 0; c < 2; c++) {
                int idx = wave * 2 + c;
                int kc = idx >> 2, rg = idx & 3;
                int row = rg * 16 + (lane >> 2);
                gload16(kbase + (size_t)row * RS + kc * 32 + (lane & 3) * 8,
                        &Ks[kc * 2048 + rg * 512]);
            }
            const u16* vbase = qkv + (size_t)(b * 1024 + (kt + 1) * 64) * RS + 1536 + h * 64;
            #pragma unroll
            for (int it = 0; it < 4; it++) {
                int d0 = dg * 16 + it * 4;
                vr[it] = *(const uint2*)(vbase + (size_t)kp * RS + d0);
            }
        }

        __builtin_amdgcn_s_setprio(1);
        #pragma unroll
        for (int kc = 0; kc < 2; kc++) {
            short8 ap[2], bv[4];
            #pragma unroll
            for (int i = 0; i < 2; i++)
                ap[i] = *(const short8*)&Ps[kc * 4096 + (wave * 32 + i * 16 + r16) * 32 + quad * 8];
            #pragma unroll
            for (int j = 0; j < 4; j++)
                bv[j] = *(const short8*)&Vt[kc * 2048 + (j * 16 + r16) * 32 + quad * 8];
            #pragma unroll
            for (int i = 0; i < 2; i++)
                #pragma unroll
                for (int j = 0; j < 4; j++)
                    O[i][j] = __builtin_amdgcn_mfma_f32_16x16x32_bf16(
                        ap[i], bv[j], O[i][j], 0, 0, 0);
        }
        __builtin_amdgcn_s_setprio(0);
    }

    // epilogue: wave-private repack through Ps (dead), coalesced 16B stores
    const int row = lane >> 2, seg = (lane & 3) * 16;
    #pragma unroll
    for (int i = 0; i < 2; i++) {
        float linv[4];
        #pragma unroll
        for (int r = 0; r < 4; r++) {
            float l = lpart[i][r];
            l += __shfl_xor(l, 1);
            l += __shfl_xor(l, 2);
            l += __shfl_xor(l, 4);
            l += __shfl_xor(l, 8);
            linv[r] = 1.0f / l;
        }
        u16* myl = &Ps[wave * 2048 + i * 1024];   // 16 rows x 64 cols
        #pragma unroll
        for (int j = 0; j < 4; j++)
            #pragma unroll
            for (int r = 0; r < 4; r++)
                myl[(quad * 4 + r) * 64 + j * 16 + r16] = f2bf(O[i][j][r] * linv[r]);
        const int token = tok0 + wave * 32 + i * 16 + row;
        const size_t oidx = (size_t)token * 768 + h * 64 + seg;
        *(ushort8v*)(out + oidx)     = *(const ushort8v*)&myl[row * 64 + seg];
        *(ushort8v*)(out + oidx + 8) = *(const ushort8v*)&myl[row * 64 + seg + 8];
    }
}

// ---------------------------------------------------------------------------
extern "C" void kernel_launch(void* const* d_in, const int* in_sizes, int n_in,
                              void* d_out, int out_size, void* d_ws, size_t ws_size,
                              hipStream_t stream)
{
    (void)in_sizes; (void)n_in; (void)out_size; (void)ws_size;
    const float* x        = (const float*)d_in[0];
    const float* ln1_g    = (const float*)d_in[1];
    const float* ln1_b    = (const float*)d_in[2];
    const float* qkv_w    = (const float*)d_in[3];
    const float* qkv_b    = (const float*)d_in[4];
    const float* proj_w   = (const float*)d_in[5];
    const float* proj_b   = (const float*)d_in[6];
    const float* c_qkv_w  = (const float*)d_in[7];
    const float* c_qkv_b  = (const float*)d_in[8];
    const float* c_proj_w = (const float*)d_in[9];
    const float* c_proj_b = (const float*)d_in[10];
    const float* cp_fc1_w = (const float*)d_in[11];
    const float* cp_fc1_b = (const float*)d_in[12];
    const float* cp_fc2_w = (const float*)d_in[13];
    const float* cp_fc2_b = (const float*)d_in[14];
    const float* P        = (const float*)d_in[15];
    const float* ln2_g    = (const float*)d_in[16];
    const float* ln2_b    = (const float*)d_in[17];
    const float* fc1_w    = (const float*)d_in[18];
    const float* fc1_b    = (const float*)d_in[19];
    const float* fc2_w    = (const float*)d_in[20];
    const float* fc2_b    = (const float*)d_in[21];

    float* out_x    = (float*)d_out;               // (8,1024,768) fp32
    float* out_dmap = out_x + 6291456;             // (8,1024,64)  fp32

    // ws layout (u16 element units)
    u16* us    = (u16*)d_ws;
    u16* n1n2  = us;                         //  6291456  n1 -> zin -> n2
    u16* bigA  = us + 6291456;               // 25165824  qkv/qkv2 ; h(3072)
    u16* ao    = bigA + 18874368;            //  6291456  attn out (tail)
    u16* y     = us + 31457280;              //  6291456
    float* xs  = (float*)(us + 37748736);    //  6291456 fp32
    u16* cph   = us + 50855936;              //   524288
    u16* Pn    = us + 51380224;              //    49152
    float* invn = (float*)(us + 51429376);   //  8192 fp32
    u16* ci    = us + 51445760;              //  canonical bf16 weights

    u16* w_qkv   = ci;                  // 1769472
    u16* w_proj  = ci + 1769472;        // 589824
    u16* w_cqkv  = ci + 2359296;        // 1769472
    u16* w_cproj = ci + 4128768;        // 589824
    u16* w_cpf1  = ci + 4718592;        // 4096
    u16* w_cpf2  = ci + 4722688;        // 49152
    u16* w_fc1   = ci + 4771840;        // 2359296
    u16* w_fc2   = ci + 7131136;        // 2359296

    // 0-2. fused prologue: weight conv + P-normalize + LN1
    {
        PrepArgs pa;
        const float* wsrc[8] = { qkv_w, proj_w, c_qkv_w, c_proj_w,
                                 cp_fc1_w, cp_fc2_w, fc1_w, fc2_w };
        u16* wdst[8] = { w_qkv, w_proj, w_cqkv, w_cproj,
                         w_cpf1, w_cpf2, w_fc1, w_fc2 };
        const int wn[8] = { 1769472, 589824, 1769472, 589824,
                            4096, 49152, 2359296, 2359296 };
        int cum = 0;
        for (int i = 0; i < 8; i++) {
            pa.conv.src[i] = wsrc[i]; pa.conv.dst[i] = wdst[i];
            pa.conv.n[i] = wn[i];
            pa.conv.nblk[i] = cum;
            cum += (wn[i] / 4 + 255) / 256;
        }
        pa.conv.nblk[8] = cum;
        pa.conv_blocks = cum;
        pa.P = P; pa.Pn = Pn;
        pa.x = x; pa.g = ln1_g; pa.bta = ln1_b;
        pa.n1 = n1n2; pa.invn = invn;
        prep_k<<<cum + 64 + 8192, 256, 0, stream>>>(pa);
    }

    // 3 + dmap branch, co-resident: qkv GEMM || (dmap fp32 + cph)
    qkv_dmap_k<<<1280, 256, 0, stream>>>(n1n2, w_qkv, qkv_b, bigA,
                                         Pn, invn, w_cpf1, cp_fc1_b,
                                         out_dmap, cph);
    // 4. attention 1
    attn_mfma<<<dim3(8, 96), 256, 0, stream>>>(bigA, ao);
    // 5+8. co-resident: y = ao @ proj_w^T + b  ||  zin = cph @ cp_fc2_w^T + b
    gemm_pair_k<<<768, 256, 0, stream>>>(ao, w_proj, proj_b, y, 768,
                                         cph, w_cpf2, cp_fc2_b, n1n2, 64);
    // 9. qkv2 = zin @ c_qkv_w^T + b
    gemm_mfma<F_BIAS | F_OUTB>
        <<<dim3(18, 64), 256, 0, stream>>>(n1n2, w_cqkv, c_qkv_b, nullptr, nullptr,
                                           bigA, nullptr, 8192, 2304, 768);
    // 10. attention 2
    attn_mfma<<<dim3(8, 96), 256, 0, stream>>>(bigA, ao);
    // 11. xs = ao2 @ c_proj_w^T + b + y + x   (y bf16, x fp32) -> fp32
    gemm_mfma<F_BIAS | F_RES1 | F_RESF | F_OUTF>
        <<<dim3(6, 64), 256, 0, stream>>>(ao, w_cproj, c_proj_b, y, x,
                                          nullptr, xs, 8192, 768, 768);
    // 12. n2 = LN(xs)
    ln_k<false><<<8192, 256, 0, stream>>>(xs, ln2_g, ln2_b, n1n2, nullptr);
    // 13. h = gelu(n2 @ fc1_w^T + b)
    gemm_mfma<F_BIAS | F_GELU | F_OUTB>
        <<<dim3(24, 64), 256, 0, stream>>>(n1n2, w_fc1, fc1_b, nullptr, nullptr,
                                           bigA, nullptr, 8192, 3072, 768);
    // 14. out = h @ fc2_w^T + b + xs  -> fp32 d_out
    gemm_mfma<F_BIAS | F_RESF | F_OUTF>
        <<<dim3(6, 64), 256, 0, stream>>>(bigA, w_fc2, fc2_b, nullptr, xs,
                                          nullptr, out_x, 8192, 768, 3072);
}